// Round 4
// baseline (257.191 us; speedup 1.0000x reference)
//
#include <hip/hip_runtime.h>
#include <stdint.h>
#include <math.h>

#define B_    4
#define H_    192
#define W_    192
#define HW    (H_*W_)            // 36864
#define NPIX  (B_*HW)            // 147456
#define C_V   10
#define C_F   64
#define C_D   16
#define C_ALL (C_V+C_F+C_D)      // 90
#define HBINS 32768              // fine bins: bits 30..16 of key
#define CBINS 256                // coarse bins: bits 30..23 of key
#define CAP   2048               // bin-b* list capacity (expected ~150)
#define NSLICE 36                // k_gather blocks per batch (36*1024 == HW)
#define NCAND (NSLICE*5)         // tail candidates per batch

// ---- workspace layout (bytes) ----
#define OFF_HIST   0u                                  // 4*32768*4 = 512KB (k_zero)
#define OFF_COARSE (4u*HBINS*4u)                       // 4*256*4 = 4KB     (k_zero)
#define ZERO_U4    ((OFF_COARSE + 4u*CBINS*4u)/16u)    // 33024 uint4s = 129*256
#define OFF_KEY    (OFF_COARSE + 4u*CBINS*4u)
#define OFF_G      (OFF_KEY + (uint32_t)NPIX*4u)
#define OFF_SELX   (OFF_G + (uint32_t)NPIX)            // zeroed by k_prep
#define OFF_RES    (OFF_SELX + (uint32_t)NPIX)         // res[12]: b2[4],usage[4],hl[4]
#define OFF_GCNT   (OFF_RES + 48u)                     // 4 uints (zeroed by k_cut)
#define OFF_GLIST  (OFF_GCNT + 16u)                    // 4*CAP*8
#define OFF_CAND   (OFF_GLIST + 4u*CAP*8u)             // 4*NCAND*8

__device__ __forceinline__ uint32_t costOf(uint32_t g) {
    return g == 0u ? 10u : (g == 1u ? 5u : 2u);
}

// budget_per_sample = float32(budget / B); usage,c exact ints ->
// usage+c <= bps  <=>  usage+c <= floor(bps)
__device__ __forceinline__ uint32_t budgetInt(const int* bptr) {
    double bps = (double)bptr[0] / (double)B_;
    float f = (float)bps;
    return (uint32_t)floorf(f);
}

// compare-exchange keeping max in x (descending order)
#define CE(x, y) { uint64_t _mn = (x) < (y) ? (x) : (y); \
                   uint64_t _mx = (x) < (y) ? (y) : (x); (x) = _mx; (y) = _mn; }

// K0: zero fine + coarse histograms (516 KB)
__global__ void k_zero(uint4* __restrict__ w4) {
    uint32_t i = blockIdx.x * blockDim.x + threadIdx.x;   // [0, 33024)
    if (i < ZERO_U4) w4[i] = make_uint4(0u, 0u, 0u, 0u);
}

// K1: per-pixel best utility / group / sortable key, zero selx,
// dual (coarse+fine) cost histograms.
__global__ void k_prep(const float* __restrict__ util, uint4* __restrict__ key4,
                       uint32_t* __restrict__ g4, uint32_t* __restrict__ selx4,
                       uint32_t* __restrict__ hist, uint32_t* __restrict__ coarse) {
    int t = blockIdx.x * blockDim.x + threadIdx.x;   // [0, NPIX/4)
    if (t >= NPIX / 4) return;
    const float4* u4 = (const float4*)util + (size_t)t * 3;
    float4 a = u4[0], b4 = u4[1], c4 = u4[2];
    float u[4][3] = { {a.x, a.y, a.z}, {a.w, b4.x, b4.y},
                      {b4.z, b4.w, c4.x}, {c4.y, c4.z, c4.w} };
    uint32_t kk[4]; uint32_t gpack = 0;
    #pragma unroll
    for (int p = 0; p < 4; ++p) {
        float best = u[p][0]; uint32_t g = 0;
        if (u[p][1] > best) { best = u[p][1]; g = 1; }   // strict > = first max
        if (u[p][2] > best) { best = u[p][2]; g = 2; }
        kk[p] = (best > 0.0f) ? (__float_as_uint(best) | 0x80000000u) : 0u;
        gpack |= g << (8 * p);
    }
    key4[t] = make_uint4(kk[0], kk[1], kk[2], kk[3]);
    g4[t] = gpack;
    selx4[t] = 0u;
    int b = (t * 4) / HW;                     // HW % 4 == 0: group never crosses batch
    #pragma unroll
    for (int p = 0; p < 4; ++p)
        if (kk[p]) {
            uint32_t c = costOf((gpack >> (8 * p)) & 3u);
            atomicAdd(&hist[(size_t)b * HBINS + ((kk[p] >> 16) & 32767u)], c);
            atomicAdd(&coarse[(size_t)b * CBINS + ((kk[p] >> 23) & 0xFFu)], c);
        }
}

// K2: 1 block, wave w handles batch w. Coarse scan (256 bins, 4/lane) ->
// crossing coarse bin; fine scan (its 128 bins, 2/lane) -> exact b2 + usage.
// Writes res (b2, usage, hl) and zeroes gcnt.
__global__ __launch_bounds__(256) void k_cut(const uint32_t* __restrict__ coarse,
                                             const uint32_t* __restrict__ hist,
                                             const int* __restrict__ budget_ptr,
                                             uint32_t* __restrict__ res,
                                             uint32_t* __restrict__ gcnt) {
    int t = threadIdx.x;
    int b = t >> 6, lane = t & 63;
    uint32_t budget = budgetInt(budget_ptr);

    // --- coarse phase: lane covers bins [hi-3 .. hi] descending ---
    const uint32_t* cb_ = coarse + (size_t)b * CBINS;
    int hi = 255 - 4 * lane;
    uint32_t c0 = cb_[hi], c1 = cb_[hi - 1], c2 = cb_[hi - 2], c3 = cb_[hi - 3];
    uint32_t cs = c0 + c1 + c2 + c3;
    uint32_t v = cs;
    #pragma unroll
    for (int off = 1; off < 64; off <<= 1) {
        uint32_t o = __shfl_up(v, off);
        if (lane >= off) v += o;
    }
    uint32_t excl = v - cs;
    bool found = (excl <= budget) && (v > budget);
    uint32_t cbin = 0, cusage = 0;
    if (found) {
        uint32_t cum = excl;
        if      (cum + c0 > budget) { cbin = (uint32_t)hi;     cusage = cum; }
        else if ((cum += c0) + c1 > budget) { cbin = (uint32_t)(hi - 1); cusage = cum; }
        else if ((cum += c1) + c2 > budget) { cbin = (uint32_t)(hi - 2); cusage = cum; }
        else                        { cbin = (uint32_t)(hi - 3); cusage = cum + c2; }
    }
    unsigned long long msk = __ballot(found);
    if (msk == 0ull) {                            // no crossing: all valid selected
        if (lane == 0) { res[b] = 0xFFFFFFFFu; res[4 + b] = 0u; res[8 + b] = 1u;
                         gcnt[b] = 0u; }
        return;
    }
    int src = __ffsll((long long)msk) - 1;
    cbin   = __shfl(cbin, src);
    cusage = __shfl(cusage, src);

    // --- fine phase: 128 bins of cbin, lane covers [fhi-1, fhi] descending ---
    const uint32_t* hb = hist + (size_t)b * HBINS + (size_t)cbin * 128;
    int fhi = 127 - 2 * lane;
    uint32_t f0 = hb[fhi], f1 = hb[fhi - 1];
    uint32_t fs = f0 + f1;
    v = fs;
    #pragma unroll
    for (int off = 1; off < 64; off <<= 1) {
        uint32_t o = __shfl_up(v, off);
        if (lane >= off) v += o;
    }
    excl = cusage + v - fs;                       // global cumsum above this chunk
    found = (excl <= budget) && (excl + fs > budget);
    uint32_t b2 = 0, fusage = 0;
    if (found) {
        if (excl + f0 > budget) { b2 = cbin * 128u + (uint32_t)fhi;       fusage = excl; }
        else                    { b2 = cbin * 128u + (uint32_t)(fhi - 1); fusage = excl + f0; }
    }
    msk = __ballot(found);
    src = __ffsll((long long)msk) - 1;            // guaranteed nonzero here
    b2     = __shfl(b2, src);
    fusage = __shfl(fusage, src);
    if (lane == 0) {
        res[b]     = b2;
        res[4 + b] = fusage;
        uint32_t bs = b2 + 32768u;
        res[8 + b] = (bs >= 65535u) ? 0xFFFFFFFFu : ((bs + 1u) << 16);
        gcnt[b] = 0u;
    }
}

// K3: wide gather — grid (NSLICE, B_), 1024 thr, ONE pixel per thread.
// bin-b* items -> global list (atomic); below-b* tail candidates ->
// wave bitonic top-4 cost-2 + top-1 cost-5 -> per-block 5 candidates.
__global__ __launch_bounds__(1024) void k_gather(const uint32_t* __restrict__ key,
                                                 const uint8_t* __restrict__ g,
                                                 const uint32_t* __restrict__ res,
                                                 uint32_t* __restrict__ gcnt,
                                                 uint64_t* __restrict__ glist,
                                                 uint64_t* __restrict__ cand) {
    int b = blockIdx.y;
    uint32_t b2 = res[b];
    if (b2 == 0xFFFFFFFFu) return;                // no crossing: nothing to do
    int t = threadIdx.x;
    int lane = t & 63, wv = t >> 6;
    uint32_t pix = blockIdx.x * 1024u + (uint32_t)t;   // [0, HW)

    __shared__ uint64_t red5[16];
    __shared__ uint64_t red2[16][4];

    uint32_t k = key[(size_t)b * HW + pix];
    uint64_t m5 = 0, a0 = 0, a1 = 0, a2 = 0, a3 = 0;
    if (k) {
        uint32_t bin = (k >> 16) & 32767u;
        if (bin == b2) {
            uint32_t gg = g[(size_t)b * HW + pix];
            uint32_t idx = atomicAdd(&gcnt[b], 1u);
            if (idx < CAP)   // asc key: (~k, pix) -> utility desc, pix asc
                glist[(size_t)b * CAP + idx] =
                    ((uint64_t)(~k) << 32) | ((uint64_t)pix << 2) | (uint64_t)gg;
        } else if (bin < b2) {
            uint32_t gg = g[(size_t)b * HW + pix];
            if (gg) {        // cost-10 (g==0) never fits: r <= 9 after bin walk
                uint64_t m = ((uint64_t)k << 18) | ((uint64_t)(65535u - pix) << 2)
                           | (uint64_t)gg;
                if (gg == 1u) m5 = m; else a0 = m;
            }
        }
    }
    // wave reduce: max for m5; bitonic top-4 merge for a0..a3 (desc sorted)
    #pragma unroll
    for (int off = 32; off; off >>= 1) {
        uint64_t o5 = __shfl_down(m5, off);
        if (o5 > m5) m5 = o5;
        uint64_t b0 = __shfl_down(a0, off), b1 = __shfl_down(a1, off),
                 b2_ = __shfl_down(a2, off), b3 = __shfl_down(a3, off);
        CE(a0, b3); CE(a1, b2_); CE(a2, b1); CE(a3, b0);
        CE(a0, a2); CE(a1, a3); CE(a0, a1); CE(a2, a3);
    }
    if (lane == 0) {
        red5[wv] = m5;
        red2[wv][0] = a0; red2[wv][1] = a1; red2[wv][2] = a2; red2[wv][3] = a3;
    }
    __syncthreads();
    if (t == 0) {
        uint64_t g5 = 0, t0 = 0, t1 = 0, t2 = 0, t3 = 0;
        for (int wq = 0; wq < 16; ++wq) {
            if (red5[wq] > g5) g5 = red5[wq];
            #pragma unroll
            for (int q = 0; q < 4; ++q) {
                uint64_t m = red2[wq][q];
                if (m > t3) {
                    if      (m > t0) { t3 = t2; t2 = t1; t1 = t0; t0 = m; }
                    else if (m > t1) { t3 = t2; t2 = t1; t1 = m; }
                    else if (m > t2) { t3 = t2; t2 = m; }
                    else             { t3 = m; }
                }
            }
        }
        uint64_t* cb_ = cand + ((size_t)b * NSLICE + blockIdx.x) * 5;
        cb_[0] = g5; cb_[1] = t0; cb_[2] = t1; cb_[3] = t2; cb_[4] = t3;
    }
}

// K4: per batch finalize — rank-sort bin-b* list, serial greedy replay,
// merge 180 tail candidates, exact <=5-pick tail simulation.
__global__ __launch_bounds__(256) void k_final(const uint32_t* __restrict__ res,
                                               const uint32_t* __restrict__ gcnt,
                                               const uint64_t* __restrict__ glist,
                                               const uint64_t* __restrict__ cand,
                                               const int* __restrict__ budget_ptr,
                                               uint8_t* __restrict__ selx) {
    int b = blockIdx.x;
    uint32_t b2 = res[b];
    if (b2 == 0xFFFFFFFFu) return;
    int t = threadIdx.x;

    __shared__ uint64_t e[CAP];
    __shared__ uint64_t s[CAP];
    __shared__ uint64_t cd[NCAND];

    uint32_t cnt = gcnt[b];
    int n = (int)(cnt < (uint32_t)CAP ? cnt : (uint32_t)CAP);
    for (int i = t; i < n; i += 256) e[i] = glist[(size_t)b * CAP + i];
    for (int i = t; i < NCAND; i += 256) cd[i] = cand[(size_t)b * NCAND + i];
    __syncthreads();

    // rank sort (composite keys distinct: pix unique per batch)
    for (int i = t; i < n; i += 256) {
        uint64_t ei = e[i];
        int rk = 0;
        for (int j = 0; j < n; ++j) rk += (e[j] < ei);
        s[rk] = ei;
    }
    __syncthreads();

    if (t == 0) {
        uint32_t budget = budgetInt(budget_ptr);
        uint32_t usage = res[4 + b];
        uint8_t* sx = selx + (size_t)b * HW;
        for (int i = 0; i < n; ++i) {
            uint64_t ei = s[i];
            uint32_t c = costOf((uint32_t)(ei & 3u));
            if (usage + c <= budget) { usage += c; sx[(ei >> 2) & 0xFFFFu] = 1; }
        }
        // merge candidates: global top-1 cost-5, top-4 cost-2
        uint64_t g5 = 0, t0 = 0, t1 = 0, t2 = 0, t3 = 0;
        for (int i = 0; i < NCAND; ++i) {
            uint64_t m = cd[i];
            if (!m) continue;
            if ((m & 3u) == 1u) { if (m > g5) g5 = m; }
            else if (m > t3) {
                if      (m > t0) { t3 = t2; t2 = t1; t1 = t0; t0 = m; }
                else if (m > t1) { t3 = t2; t2 = t1; t1 = m; }
                else if (m > t2) { t3 = t2; t2 = m; }
                else             { t3 = m; }
            }
        }
        uint64_t c5[5] = { g5, t0, t1, t2, t3 };
        for (int i = 1; i < 5; ++i) {             // insertion sort desc
            uint64_t x = c5[i]; int j = i;
            while (j > 0 && c5[j - 1] < x) { c5[j] = c5[j - 1]; --j; }
            c5[j] = x;
        }
        // exact replay of the greedy below bin b* (desc walk order)
        uint32_t r = budget - usage;              // provably <= 9
        for (int i = 0; i < 5; ++i) {
            uint64_t m = c5[i];
            if (!m) break;
            uint32_t c = costOf((uint32_t)(m & 3u));
            if (c <= r) {
                r -= c;
                uint32_t pix = 65535u - (uint32_t)((m >> 2) & 0xFFFFu);
                sx[pix] = 1;
            }
        }
    }
}

// K5: masked sparse BEV + sel_idx output (c==0 blocks), float4-vectorized.
__global__ void k_sparse(const float* __restrict__ collab, const uint4* __restrict__ key4,
                         const uint32_t* __restrict__ g4, const uint32_t* __restrict__ selx4,
                         const uint32_t* __restrict__ hl_arr,
                         float* __restrict__ out, float* __restrict__ selOut) {
    int tid = blockIdx.x * blockDim.x + threadIdx.x;   // [0, HW/4)
    int c = blockIdx.y, b = blockIdx.z;
    int cls = (c < C_V) ? 0 : ((c < C_V + C_F) ? 1 : 2);
    uint32_t hl = hl_arr[b];                           // >= 1 always
    size_t p4 = (size_t)b * (HW / 4) + (size_t)tid;
    uint4 kk = key4[p4];
    uint32_t gg = g4[p4];
    uint32_t sx = selx4[p4];
    int sc[4];
    uint32_t kv[4] = { kk.x, kk.y, kk.z, kk.w };
    #pragma unroll
    for (int p = 0; p < 4; ++p) {
        bool se = (kv[p] >= hl) || (((sx >> (8 * p)) & 0xFFu) != 0u);
        sc[p] = se ? (int)((gg >> (8 * p)) & 3u) : -1;
    }
    size_t co = ((size_t)(b * C_ALL + c)) * HW + (size_t)tid * 4;
    float4 v = *(const float4*)(collab + co);
    float4 o;
    o.x = (sc[0] == cls) ? v.x : 0.0f;
    o.y = (sc[1] == cls) ? v.y : 0.0f;
    o.z = (sc[2] == cls) ? v.z : 0.0f;
    o.w = (sc[3] == cls) ? v.w : 0.0f;
    *(float4*)(out + co) = o;
    if (c == 0) {
        float4 sf = make_float4((float)sc[0], (float)sc[1], (float)sc[2], (float)sc[3]);
        ((float4*)selOut)[p4] = sf;
    }
}

extern "C" void kernel_launch(void* const* d_in, const int* in_sizes, int n_in,
                              void* d_out, int out_size, void* d_ws, size_t ws_size,
                              hipStream_t stream) {
    (void)in_sizes; (void)n_in; (void)out_size; (void)ws_size;
    const float* collab = (const float*)d_in[0];
    const float* util   = (const float*)d_in[1];
    const int*   budget = (const int*)d_in[2];

    uint8_t*  ws     = (uint8_t*)d_ws;
    uint32_t* hist   = (uint32_t*)(ws + OFF_HIST);
    uint32_t* coarse = (uint32_t*)(ws + OFF_COARSE);
    uint32_t* key    = (uint32_t*)(ws + OFF_KEY);
    uint8_t*  g      = ws + OFF_G;
    uint8_t*  selx   = ws + OFF_SELX;
    uint32_t* res    = (uint32_t*)(ws + OFF_RES);
    uint32_t* gcnt   = (uint32_t*)(ws + OFF_GCNT);
    uint64_t* glist  = (uint64_t*)(ws + OFF_GLIST);
    uint64_t* cand   = (uint64_t*)(ws + OFF_CAND);

    float* outSparse = (float*)d_out;
    float* outSel    = outSparse + (size_t)B_ * C_ALL * HW;

    k_zero  <<<(ZERO_U4 + 255) / 256, 256, 0, stream>>>((uint4*)ws);
    k_prep  <<<(NPIX / 4 + 255) / 256, 256, 0, stream>>>(util, (uint4*)key, (uint32_t*)g,
                                                         (uint32_t*)selx, hist, coarse);
    k_cut   <<<1, 256, 0, stream>>>(coarse, hist, budget, res, gcnt);
    dim3 gridG(NSLICE, B_);
    k_gather<<<gridG, 1024, 0, stream>>>(key, g, res, gcnt, glist, cand);
    k_final <<<B_, 256, 0, stream>>>(res, gcnt, glist, cand, budget, selx);
    dim3 grid3(HW / 4 / 256, C_ALL, B_);
    k_sparse<<<grid3, 256, 0, stream>>>(collab, (const uint4*)key, (const uint32_t*)g,
                                        (const uint32_t*)selx, res + 8, outSparse, outSel);
}

// Round 5
// 103.656 us; speedup vs baseline: 2.4812x; 2.4812x over previous
//
#include <hip/hip_runtime.h>
#include <stdint.h>
#include <math.h>

#define B_    4
#define H_    192
#define W_    192
#define HW    (H_*W_)            // 36864
#define NPIX  (B_*HW)            // 147456
#define C_V   10
#define C_F   64
#define C_D   16
#define C_ALL (C_V+C_F+C_D)      // 90
#define HBINS 32768              // fine bins: bits 30..16 of key
#define CAP   2048               // bin-b* list capacity (expected ~150)
#define NSLICE 36                // k_gather blocks per batch (36*1024 == HW)
#define NCAND (NSLICE*5)         // tail candidates per batch

// ---- workspace layout (bytes) ----
#define OFF_HIST   0u                                  // 4*32768*4 = 512KB (k_zero)
#define ZERO_U4    ((4u*HBINS*4u)/16u)                 // 32768 uint4s
#define OFF_KEY    (4u*HBINS*4u)
#define OFF_G      (OFF_KEY + (uint32_t)NPIX*4u)
#define OFF_SELX   (OFF_G + (uint32_t)NPIX)            // zeroed by k_prep
#define OFF_RES    (OFF_SELX + (uint32_t)NPIX)         // res[12]: b2[4],usage[4],hl[4]
#define OFF_GCNT   (OFF_RES + 48u)                     // 4 uints (zeroed by k_cut)
#define OFF_GLIST  (OFF_GCNT + 16u)                    // 4*CAP*8
#define OFF_CAND   (OFF_GLIST + 4u*CAP*8u)             // 4*NCAND*8

__device__ __forceinline__ uint32_t costOf(uint32_t g) {
    return g == 0u ? 10u : (g == 1u ? 5u : 2u);
}

// budget_per_sample = float32(budget / B); usage,c exact ints ->
// usage+c <= bps  <=>  usage+c <= floor(bps)
__device__ __forceinline__ uint32_t budgetInt(const int* bptr) {
    double bps = (double)bptr[0] / (double)B_;
    float f = (float)bps;
    return (uint32_t)floorf(f);
}

// compare-exchange keeping max in x (descending order)
#define CE(x, y) { uint64_t _mn = (x) < (y) ? (x) : (y); \
                   uint64_t _mx = (x) < (y) ? (y) : (x); (x) = _mx; (y) = _mn; }

// K0: zero fine histogram (512 KB)
__global__ void k_zero(uint4* __restrict__ w4) {
    uint32_t i = blockIdx.x * blockDim.x + threadIdx.x;   // [0, 32768)
    w4[i] = make_uint4(0u, 0u, 0u, 0u);
}

// K1: per-pixel best utility / group / sortable key, zero selx, FINE hist only
// (coarse hist removed: exponent-concentrated atomics serialized -> 185us in R4).
__global__ void k_prep(const float* __restrict__ util, uint4* __restrict__ key4,
                       uint32_t* __restrict__ g4, uint32_t* __restrict__ selx4,
                       uint32_t* __restrict__ hist) {
    int t = blockIdx.x * blockDim.x + threadIdx.x;   // [0, NPIX/4)
    if (t >= NPIX / 4) return;
    const float4* u4 = (const float4*)util + (size_t)t * 3;
    float4 a = u4[0], b4 = u4[1], c4 = u4[2];
    float u[4][3] = { {a.x, a.y, a.z}, {a.w, b4.x, b4.y},
                      {b4.z, b4.w, c4.x}, {c4.y, c4.z, c4.w} };
    uint32_t kk[4]; uint32_t gpack = 0;
    #pragma unroll
    for (int p = 0; p < 4; ++p) {
        float best = u[p][0]; uint32_t g = 0;
        if (u[p][1] > best) { best = u[p][1]; g = 1; }   // strict > = first max
        if (u[p][2] > best) { best = u[p][2]; g = 2; }
        kk[p] = (best > 0.0f) ? (__float_as_uint(best) | 0x80000000u) : 0u;
        gpack |= g << (8 * p);
    }
    key4[t] = make_uint4(kk[0], kk[1], kk[2], kk[3]);
    g4[t] = gpack;
    selx4[t] = 0u;
    int b = (t * 4) / HW;                     // HW % 4 == 0: group never crosses batch
    #pragma unroll
    for (int p = 0; p < 4; ++p)
        if (kk[p])
            atomicAdd(&hist[(size_t)b * HBINS + ((kk[p] >> 16) & 32767u)],
                      costOf((gpack >> (8 * p)) & 3u));
}

// K2: grid = B_ blocks x 256 thr. Phase 1 (all): thread t sums fine bins
// [128t,128t+128) -> LDS coarse csum[256] (no atomics, L2-hot). Phase 2+3
// (wave 0): coarse shfl-scan -> crossing coarse bin; fine scan of its 128
// bins -> exact b2 + usage. Writes res (b2, usage, hl), zeroes gcnt.
__global__ __launch_bounds__(256) void k_cut(const uint32_t* __restrict__ hist,
                                             const int* __restrict__ budget_ptr,
                                             uint32_t* __restrict__ res,
                                             uint32_t* __restrict__ gcnt) {
    int b = blockIdx.x;
    int t = threadIdx.x;
    int lane = t & 63, wv = t >> 6;
    uint32_t budget = budgetInt(budget_ptr);
    const uint32_t* hb = hist + (size_t)b * HBINS;

    __shared__ uint32_t csum[256];

    // --- Phase 1: coarse sums from fine hist ---
    const uint4* h4 = (const uint4*)(hb + (size_t)t * 128);
    uint32_t s = 0;
    #pragma unroll 8
    for (int j = 0; j < 32; ++j) { uint4 v = h4[j]; s += v.x + v.y + v.z + v.w; }
    csum[t] = s;
    __syncthreads();
    if (wv != 0) return;                          // no further barriers below

    // --- Phase 2: coarse descending cumsum (wave 0, 4 bins/lane) ---
    int hi = 255 - 4 * lane;
    uint32_t c0 = csum[hi], c1 = csum[hi - 1], c2 = csum[hi - 2], c3 = csum[hi - 3];
    uint32_t cs = c0 + c1 + c2 + c3;
    uint32_t v = cs;
    #pragma unroll
    for (int off = 1; off < 64; off <<= 1) {
        uint32_t o = __shfl_up(v, off);
        if (lane >= off) v += o;
    }
    uint32_t excl = v - cs;
    bool found = (excl <= budget) && (v > budget);
    uint32_t cbin = 0, cusage = 0;
    if (found) {
        uint32_t cum = excl;
        if      (cum + c0 > budget) { cbin = (uint32_t)hi;     cusage = cum; }
        else if ((cum += c0) + c1 > budget) { cbin = (uint32_t)(hi - 1); cusage = cum; }
        else if ((cum += c1) + c2 > budget) { cbin = (uint32_t)(hi - 2); cusage = cum; }
        else                        { cbin = (uint32_t)(hi - 3); cusage = cum + c2; }
    }
    unsigned long long msk = __ballot(found);
    if (msk == 0ull) {                            // no crossing: all valid selected
        if (lane == 0) { res[b] = 0xFFFFFFFFu; res[4 + b] = 0u; res[8 + b] = 1u;
                         gcnt[b] = 0u; }
        return;
    }
    int src = __ffsll((long long)msk) - 1;
    cbin   = __shfl(cbin, src);
    cusage = __shfl(cusage, src);

    // --- Phase 3: fine scan of cbin's 128 bins (wave 0, 2/lane) ---
    const uint32_t* fb = hb + (size_t)cbin * 128;
    int fhi = 127 - 2 * lane;
    uint32_t f0 = fb[fhi], f1 = fb[fhi - 1];
    uint32_t fs = f0 + f1;
    v = fs;
    #pragma unroll
    for (int off = 1; off < 64; off <<= 1) {
        uint32_t o = __shfl_up(v, off);
        if (lane >= off) v += o;
    }
    excl = cusage + v - fs;                       // global cumsum above this chunk
    found = (excl <= budget) && (excl + fs > budget);
    uint32_t b2 = 0, fusage = 0;
    if (found) {
        if (excl + f0 > budget) { b2 = cbin * 128u + (uint32_t)fhi;       fusage = excl; }
        else                    { b2 = cbin * 128u + (uint32_t)(fhi - 1); fusage = excl + f0; }
    }
    msk = __ballot(found);
    src = __ffsll((long long)msk) - 1;            // guaranteed nonzero here
    b2     = __shfl(b2, src);
    fusage = __shfl(fusage, src);
    if (lane == 0) {
        res[b]     = b2;
        res[4 + b] = fusage;
        uint32_t bs = b2 + 32768u;
        res[8 + b] = (bs >= 65535u) ? 0xFFFFFFFFu : ((bs + 1u) << 16);
        gcnt[b] = 0u;
    }
}

// K3: wide gather — grid (NSLICE, B_), 1024 thr, ONE pixel per thread.
// bin-b* items -> global list (atomic); below-b* tail candidates ->
// wave bitonic top-4 cost-2 + top-1 cost-5 -> per-block 5 candidates.
__global__ __launch_bounds__(1024) void k_gather(const uint32_t* __restrict__ key,
                                                 const uint8_t* __restrict__ g,
                                                 const uint32_t* __restrict__ res,
                                                 uint32_t* __restrict__ gcnt,
                                                 uint64_t* __restrict__ glist,
                                                 uint64_t* __restrict__ cand) {
    int b = blockIdx.y;
    uint32_t b2 = res[b];
    if (b2 == 0xFFFFFFFFu) return;                // no crossing: nothing to do
    int t = threadIdx.x;
    int lane = t & 63, wv = t >> 6;
    uint32_t pix = blockIdx.x * 1024u + (uint32_t)t;   // [0, HW)

    __shared__ uint64_t red5[16];
    __shared__ uint64_t red2[16][4];

    uint32_t k = key[(size_t)b * HW + pix];
    uint64_t m5 = 0, a0 = 0, a1 = 0, a2 = 0, a3 = 0;
    if (k) {
        uint32_t bin = (k >> 16) & 32767u;
        if (bin == b2) {
            uint32_t gg = g[(size_t)b * HW + pix];
            uint32_t idx = atomicAdd(&gcnt[b], 1u);
            if (idx < CAP)   // asc key: (~k, pix) -> utility desc, pix asc
                glist[(size_t)b * CAP + idx] =
                    ((uint64_t)(~k) << 32) | ((uint64_t)pix << 2) | (uint64_t)gg;
        } else if (bin < b2) {
            uint32_t gg = g[(size_t)b * HW + pix];
            if (gg) {        // cost-10 (g==0) never fits: r <= 9 after bin walk
                uint64_t m = ((uint64_t)k << 18) | ((uint64_t)(65535u - pix) << 2)
                           | (uint64_t)gg;
                if (gg == 1u) m5 = m; else a0 = m;
            }
        }
    }
    // wave reduce: max for m5; bitonic top-4 merge for a0..a3 (desc sorted)
    #pragma unroll
    for (int off = 32; off; off >>= 1) {
        uint64_t o5 = __shfl_down(m5, off);
        if (o5 > m5) m5 = o5;
        uint64_t b0 = __shfl_down(a0, off), b1 = __shfl_down(a1, off),
                 b2_ = __shfl_down(a2, off), b3 = __shfl_down(a3, off);
        CE(a0, b3); CE(a1, b2_); CE(a2, b1); CE(a3, b0);
        CE(a0, a2); CE(a1, a3); CE(a0, a1); CE(a2, a3);
    }
    if (lane == 0) {
        red5[wv] = m5;
        red2[wv][0] = a0; red2[wv][1] = a1; red2[wv][2] = a2; red2[wv][3] = a3;
    }
    __syncthreads();
    if (t == 0) {
        uint64_t g5 = 0, t0 = 0, t1 = 0, t2 = 0, t3 = 0;
        for (int wq = 0; wq < 16; ++wq) {
            if (red5[wq] > g5) g5 = red5[wq];
            #pragma unroll
            for (int q = 0; q < 4; ++q) {
                uint64_t m = red2[wq][q];
                if (m > t3) {
                    if      (m > t0) { t3 = t2; t2 = t1; t1 = t0; t0 = m; }
                    else if (m > t1) { t3 = t2; t2 = t1; t1 = m; }
                    else if (m > t2) { t3 = t2; t2 = m; }
                    else             { t3 = m; }
                }
            }
        }
        uint64_t* cb_ = cand + ((size_t)b * NSLICE + blockIdx.x) * 5;
        cb_[0] = g5; cb_[1] = t0; cb_[2] = t1; cb_[3] = t2; cb_[4] = t3;
    }
}

// K4: per batch finalize — rank-sort bin-b* list, serial greedy replay,
// merge 180 tail candidates, exact <=5-pick tail simulation.
__global__ __launch_bounds__(256) void k_final(const uint32_t* __restrict__ res,
                                               const uint32_t* __restrict__ gcnt,
                                               const uint64_t* __restrict__ glist,
                                               const uint64_t* __restrict__ cand,
                                               const int* __restrict__ budget_ptr,
                                               uint8_t* __restrict__ selx) {
    int b = blockIdx.x;
    uint32_t b2 = res[b];
    if (b2 == 0xFFFFFFFFu) return;
    int t = threadIdx.x;

    __shared__ uint64_t e[CAP];
    __shared__ uint64_t s[CAP];
    __shared__ uint64_t cd[NCAND];

    uint32_t cnt = gcnt[b];
    int n = (int)(cnt < (uint32_t)CAP ? cnt : (uint32_t)CAP);
    for (int i = t; i < n; i += 256) e[i] = glist[(size_t)b * CAP + i];
    for (int i = t; i < NCAND; i += 256) cd[i] = cand[(size_t)b * NCAND + i];
    __syncthreads();

    // rank sort (composite keys distinct: pix unique per batch)
    for (int i = t; i < n; i += 256) {
        uint64_t ei = e[i];
        int rk = 0;
        for (int j = 0; j < n; ++j) rk += (e[j] < ei);
        s[rk] = ei;
    }
    __syncthreads();

    if (t == 0) {
        uint32_t budget = budgetInt(budget_ptr);
        uint32_t usage = res[4 + b];
        uint8_t* sx = selx + (size_t)b * HW;
        for (int i = 0; i < n; ++i) {
            uint64_t ei = s[i];
            uint32_t c = costOf((uint32_t)(ei & 3u));
            if (usage + c <= budget) { usage += c; sx[(ei >> 2) & 0xFFFFu] = 1; }
        }
        // merge candidates: global top-1 cost-5, top-4 cost-2
        uint64_t g5 = 0, t0 = 0, t1 = 0, t2 = 0, t3 = 0;
        for (int i = 0; i < NCAND; ++i) {
            uint64_t m = cd[i];
            if (!m) continue;
            if ((m & 3u) == 1u) { if (m > g5) g5 = m; }
            else if (m > t3) {
                if      (m > t0) { t3 = t2; t2 = t1; t1 = t0; t0 = m; }
                else if (m > t1) { t3 = t2; t2 = t1; t1 = m; }
                else if (m > t2) { t3 = t2; t2 = m; }
                else             { t3 = m; }
            }
        }
        uint64_t c5[5] = { g5, t0, t1, t2, t3 };
        for (int i = 1; i < 5; ++i) {             // insertion sort desc
            uint64_t x = c5[i]; int j = i;
            while (j > 0 && c5[j - 1] < x) { c5[j] = c5[j - 1]; --j; }
            c5[j] = x;
        }
        // exact replay of the greedy below bin b* (desc walk order)
        uint32_t r = budget - usage;              // provably <= 9
        for (int i = 0; i < 5; ++i) {
            uint64_t m = c5[i];
            if (!m) break;
            uint32_t c = costOf((uint32_t)(m & 3u));
            if (c <= r) {
                r -= c;
                uint32_t pix = 65535u - (uint32_t)((m >> 2) & 0xFFFFu);
                sx[pix] = 1;
            }
        }
    }
}

// K5: masked sparse BEV + sel_idx output (c==0 blocks), float4-vectorized.
__global__ void k_sparse(const float* __restrict__ collab, const uint4* __restrict__ key4,
                         const uint32_t* __restrict__ g4, const uint32_t* __restrict__ selx4,
                         const uint32_t* __restrict__ hl_arr,
                         float* __restrict__ out, float* __restrict__ selOut) {
    int tid = blockIdx.x * blockDim.x + threadIdx.x;   // [0, HW/4)
    int c = blockIdx.y, b = blockIdx.z;
    int cls = (c < C_V) ? 0 : ((c < C_V + C_F) ? 1 : 2);
    uint32_t hl = hl_arr[b];                           // >= 1 always
    size_t p4 = (size_t)b * (HW / 4) + (size_t)tid;
    uint4 kk = key4[p4];
    uint32_t gg = g4[p4];
    uint32_t sx = selx4[p4];
    int sc[4];
    uint32_t kv[4] = { kk.x, kk.y, kk.z, kk.w };
    #pragma unroll
    for (int p = 0; p < 4; ++p) {
        bool se = (kv[p] >= hl) || (((sx >> (8 * p)) & 0xFFu) != 0u);
        sc[p] = se ? (int)((gg >> (8 * p)) & 3u) : -1;
    }
    size_t co = ((size_t)(b * C_ALL + c)) * HW + (size_t)tid * 4;
    float4 v = *(const float4*)(collab + co);
    float4 o;
    o.x = (sc[0] == cls) ? v.x : 0.0f;
    o.y = (sc[1] == cls) ? v.y : 0.0f;
    o.z = (sc[2] == cls) ? v.z : 0.0f;
    o.w = (sc[3] == cls) ? v.w : 0.0f;
    *(float4*)(out + co) = o;
    if (c == 0) {
        float4 sf = make_float4((float)sc[0], (float)sc[1], (float)sc[2], (float)sc[3]);
        ((float4*)selOut)[p4] = sf;
    }
}

extern "C" void kernel_launch(void* const* d_in, const int* in_sizes, int n_in,
                              void* d_out, int out_size, void* d_ws, size_t ws_size,
                              hipStream_t stream) {
    (void)in_sizes; (void)n_in; (void)out_size; (void)ws_size;
    const float* collab = (const float*)d_in[0];
    const float* util   = (const float*)d_in[1];
    const int*   budget = (const int*)d_in[2];

    uint8_t*  ws     = (uint8_t*)d_ws;
    uint32_t* hist   = (uint32_t*)(ws + OFF_HIST);
    uint32_t* key    = (uint32_t*)(ws + OFF_KEY);
    uint8_t*  g      = ws + OFF_G;
    uint8_t*  selx   = ws + OFF_SELX;
    uint32_t* res    = (uint32_t*)(ws + OFF_RES);
    uint32_t* gcnt   = (uint32_t*)(ws + OFF_GCNT);
    uint64_t* glist  = (uint64_t*)(ws + OFF_GLIST);
    uint64_t* cand   = (uint64_t*)(ws + OFF_CAND);

    float* outSparse = (float*)d_out;
    float* outSel    = outSparse + (size_t)B_ * C_ALL * HW;

    k_zero  <<<ZERO_U4 / 256, 256, 0, stream>>>((uint4*)ws);
    k_prep  <<<(NPIX / 4 + 255) / 256, 256, 0, stream>>>(util, (uint4*)key, (uint32_t*)g,
                                                         (uint32_t*)selx, hist);
    k_cut   <<<B_, 256, 0, stream>>>(hist, budget, res, gcnt);
    dim3 gridG(NSLICE, B_);
    k_gather<<<gridG, 1024, 0, stream>>>(key, g, res, gcnt, glist, cand);
    k_final <<<B_, 256, 0, stream>>>(res, gcnt, glist, cand, budget, selx);
    dim3 grid3(HW / 4 / 256, C_ALL, B_);
    k_sparse<<<grid3, 256, 0, stream>>>(collab, (const uint4*)key, (const uint32_t*)g,
                                        (const uint32_t*)selx, res + 8, outSparse, outSel);
}